// Round 5
// baseline (187.075 us; speedup 1.0000x reference)
//
#include <hip/hip_runtime.h>
#include <hip/hip_bf16.h>
#include <stdint.h>

// Problem constants (fixed by setup_inputs)
#define NN 10000
#define EE 160000
#define BB 2
#define TT 12
#define FF 16
#define HG 32
#define HH 64
#define PP 4
#define BT (BB*TT)   // 24
#define MM (BB*NN)   // 20000
#define CAP 96       // fixed CSR capacity/node: deg ~ Binom(160k,1e-4), 20 sigma
#define L2E 1.4426950408889634f
#define SL 3         // bt slices (8 bt each): slice = 2.56 MB -> fits 4MB XCD L2
#define SBT 8

typedef _Float16 half8 __attribute__((ext_vector_type(8)));
typedef _Float16 h2 __attribute__((ext_vector_type(2)));
typedef float f32x4 __attribute__((ext_vector_type(4)));

union UP { uint32_t u; h2 h; };
union H8U { uint32_t u[4]; half8 v; };

// a pre-scaled by log2(e): sigmoid(x) = rcp(1 + exp2(-L*x))
__device__ __forceinline__ float sigm2(float a) {
  return __builtin_amdgcn_rcpf(1.0f + __builtin_amdgcn_exp2f(-a));
}
// a pre-scaled by 2*log2(e): tanh(x) = 1 - 2*rcp(1 + exp2(2L*x))
__device__ __forceinline__ float tanh2(float a) {
  return fmaf(-2.0f, __builtin_amdgcn_rcpf(1.0f + __builtin_amdgcn_exp2f(a)), 1.0f);
}
// g-gate: returns (2*L2E)*tanh(x); lets c be carried pre-scaled by 2*L2E.
__device__ __forceinline__ float tanh2g(float a) {
  return fmaf(-2.0f * (2.0f * L2E),
              __builtin_amdgcn_rcpf(1.0f + __builtin_amdgcn_exp2f(a)),
              2.0f * L2E);
}

// lgkm-only barrier (neutral vs __syncthreads per r2 A/B; never worse)
__device__ __forceinline__ void barrier_lds() {
  asm volatile("s_waitcnt lgkmcnt(0)" ::: "memory");
  __builtin_amdgcn_s_barrier();
  asm volatile("" ::: "memory");
}

// ---- merged: CSR build + era5 transpose (slice-major) + weight pre-pack ----
// xt layout: [s][n][btl][fp] f16-pairs -> row (s,n) = 64 dwords = 256 B.
// wbuf layout: dword e of thread t at wbuf[e*256+t] (lane-interleaved).
//   e 0..3 bias1[g] | 4..7 bias2[g] | 8..11 wx[g]
//   e 12..27  Bx[g] | 28..59 Bh1[g][c2] | 60..91 Bh2[g][c2] | 92..99 Bg[nt]
#define FILL_BLKS (EE / 256)              // 625
#define PREP_BLKS ((NN * BT * 8) / 256)   // 7500
__global__ __launch_bounds__(256) void k_prepfill(
    const int* __restrict__ eidx, int* __restrict__ cnt, int* __restrict__ csr,
    const float* __restrict__ era5, uint32_t* __restrict__ xt,
    const float* __restrict__ gcn_w,
    const float* __restrict__ w_ih1, const float* __restrict__ w_hh1,
    const float* __restrict__ b_ih1, const float* __restrict__ b_hh1,
    const float* __restrict__ w_ih2, const float* __restrict__ w_hh2,
    const float* __restrict__ b_ih2, const float* __restrict__ b_hh2,
    uint32_t* __restrict__ wbuf) {
  const int bid = blockIdx.x;
  const int tid = threadIdx.x;
  if (bid < FILL_BLKS) {
    int e = bid * 256 + tid;
    int d = eidx[EE + e];
    int pos = atomicAdd(&cnt[d], 1);
    if (pos < CAP) csr[d * CAP + pos] = eidx[e];
    return;
  }
  if (bid < FILL_BLKS + PREP_BLKS) {
    int D = (bid - FILL_BLKS) * 256 + tid;  // dword index into xt
    int s = D / (NN * 64);
    int rem = D - s * (NN * 64);
    int n = rem >> 6;
    int l = rem & 63;
    int btl = l >> 3, fp = l & 7;
    int bt = s * SBT + btl;
    const float* src = era5 + ((size_t)bt * NN + n) * FF + fp * 2;
    UP u; u.h[0] = (_Float16)src[0]; u.h[1] = (_Float16)src[1];
    xt[D] = u.u;
    return;
  }
  // ---- weight pre-pack (single block) ----
  const int wave = tid >> 6;
  const int lane = tid & 63;
  const int col = lane & 15;
  const int quad = lane >> 4;
#pragma unroll
  for (int g = 0; g < 4; ++g) {
    const float sc = (g == 2) ? 2.0f * L2E : L2E;
    int ncol = 16 * (wave + 4 * g) + col;
    wbuf[(0 + g) * 256 + tid] = __float_as_uint((b_ih1[ncol] + b_hh1[ncol]) * sc);
    wbuf[(4 + g) * 256 + tid] = __float_as_uint((b_ih2[ncol] + b_hh2[ncol]) * sc);
    wbuf[(8 + g) * 256 + tid] = __float_as_uint(w_ih2[ncol] * sc);
    H8U bx;
#pragma unroll
    for (int j = 0; j < 8; ++j)
      bx.v[j] = (_Float16)(w_ih1[ncol * HG + quad * 8 + j] * sc);
#pragma unroll
    for (int d = 0; d < 4; ++d) wbuf[(12 + g * 4 + d) * 256 + tid] = bx.u[d];
#pragma unroll
    for (int c2 = 0; c2 < 2; ++c2) {
      H8U b1, b2;
#pragma unroll
      for (int j = 0; j < 8; ++j) {
        b1.v[j] = (_Float16)(w_hh1[ncol * HH + c2 * 32 + quad * 8 + j] * sc);
        b2.v[j] = (_Float16)(w_hh2[ncol * HH + c2 * 32 + quad * 8 + j] * sc);
      }
#pragma unroll
      for (int d = 0; d < 4; ++d) {
        wbuf[(28 + (g * 2 + c2) * 4 + d) * 256 + tid] = b1.u[d];
        wbuf[(60 + (g * 2 + c2) * 4 + d) * 256 + tid] = b2.u[d];
      }
    }
  }
  // gcn_w B-fragments: B[k][n], k=f (0..15 valid, 16..31 zero), n = nt*16+col
#pragma unroll
  for (int nt = 0; nt < 2; ++nt) {
#pragma unroll
    for (int d = 0; d < 4; ++d) {
      int k0 = quad * 8 + d * 2;
      int c = nt * 16 + col;
      UP u;
      u.h[0] = (k0 < FF)     ? (_Float16)gcn_w[k0 * HG + c]       : (_Float16)0.f;
      u.h[1] = (k0 + 1 < FF) ? (_Float16)gcn_w[(k0 + 1) * HG + c] : (_Float16)0.f;
      wbuf[(92 + nt * 4 + d) * 256 + tid] = u.u;
    }
  }
}

// ---- GCN aggregate, bt-sliced so the active xt slice is L2-resident ----
// r4 analysis: 160K edges x 768 B = 123 MB of random-row reads vs 7.68 MB xt
// that does NOT fit a 4 MB XCD L2 -> ~50% LLC misses at 500+ cy. Slicing bt
// into 3 x 8 keeps the working slice at 2.56 MB (L2-resident on every XCD);
// s-major blockIdx ordering keeps all XCDs on the same slice at the same time.
// Per-src read is now 1 dword/lane. Epilogue: 2 MFMAs per (dst, slice).
__global__ __launch_bounds__(256) void k_gather(const uint32_t* __restrict__ xt,
                                                const int* __restrict__ csr,
                                                const int* __restrict__ cnt,
                                                const float* __restrict__ gb,
                                                const uint32_t* __restrict__ wbuf,
                                                _Float16* __restrict__ gout) {
  __shared__ __align__(16) _Float16 aggh[4][16][40];   // 5120 B, rows 8..15 zero
  const int tid = threadIdx.x;
  const int dloc = tid >> 6, lane = tid & 63;
  const int col = lane & 15, quad = lane >> 4;
  const int s = blockIdx.x / (NN / 4);
  const int b2 = blockIdx.x - s * (NN / 4);

  // zero own slice (320 dwords per wave, 5 per lane) — wave-private, no barrier
  uint32_t* az = (uint32_t*)&aggh[dloc][0][0];
#pragma unroll
  for (int i = 0; i < 5; ++i) az[lane + 64 * i] = 0u;

  H8U Bg[2];
#pragma unroll
  for (int nt = 0; nt < 2; ++nt)
#pragma unroll
    for (int d = 0; d < 4; ++d) Bg[nt].u[d] = wbuf[(92 + nt * 4 + d) * 256 + tid];
  const float b0 = gb[col], b1 = gb[16 + col];

  const int dst = b2 * 4 + dloc;
  const int cdst = min(cnt[dst], CAP);
  const float dinv_d = rsqrtf((float)cdst + 1.0f);
  const uint32_t* xs = xt + (size_t)s * NN * 64;

  float a0 = 0.f, a1v = 0.f;   // lane owns (btl = lane>>3, f-pair = lane&7)
  for (int base = 0; base < cdst; base += 64) {
    int mine = base + lane;
    int sv = dst; float dvv = 0.f;   // padding: valid row, zero weight
    if (mine < cdst) {
      sv = csr[dst * CAP + mine];
      dvv = rsqrtf((float)cnt[sv] + 1.0f);
    }
    const int lim = min(64, cdst - base);
    for (int j = 0; j < lim; j += 8) {
      int sj[8]; float dj[8];
#pragma unroll
      for (int u = 0; u < 8; ++u) {
        int idx = j + u;
        sj[u] = __shfl(sv, idx);
        float d = __shfl(dvv, idx);
        dj[u] = (idx < lim) ? d : 0.f;
      }
      uint32_t dw[8];
#pragma unroll
      for (int u = 0; u < 8; ++u) dw[u] = xs[(size_t)sj[u] * 64 + lane];
#pragma unroll
      for (int u = 0; u < 8; ++u) {
        UP up; up.u = dw[u];
        a0  = fmaf((float)up.h[0], dj[u], a0);
        a1v = fmaf((float)up.h[1], dj[u], a1v);
      }
    }
  }
  // self term + symmetric normalization; store agg pair (wave-private LDS)
  UP st; st.u = xs[(size_t)dst * 64 + lane];
  UP o;
  o.h[0] = (_Float16)((a0  + (float)st.h[0] * dinv_d) * dinv_d);
  o.h[1] = (_Float16)((a1v + (float)st.h[1] * dinv_d) * dinv_d);
  *(uint32_t*)&aggh[dloc][lane >> 3][(lane & 7) * 2] = o.u;

  // same-wave readback; A-frag: m = col (rows 8..15 zero), k = quad*8+j
  const half8 Af = *(const half8*)&aggh[dloc][col][quad * 8];
  f32x4 C[2];
#pragma unroll
  for (int nt = 0; nt < 2; ++nt) {
    float bb = nt ? b1 : b0;
    f32x4 ci; ci[0] = bb; ci[1] = bb; ci[2] = bb; ci[3] = bb;
    C[nt] = __builtin_amdgcn_mfma_f32_16x16x32_f16(Af, Bg[nt].v, ci, 0, 0, 0);
  }
  // C: out-row = quad*4+r (valid 0..7), out-col = col
  if (quad < 2) {
#pragma unroll
    for (int r = 0; r < 4; ++r) {
      int bt = s * SBT + quad * 4 + r;
      int bb = (bt >= TT) ? 1 : 0;
      int t = bt - bb * TT;
#pragma unroll
      for (int nt = 0; nt < 2; ++nt)
        gout[((size_t)(bb * NN + dst)) * 384 + t * 32 + nt * 16 + col] =
            (_Float16)C[nt][r];
    }
  }
}

// -------- fused dual LSTM + FC; 512-thread block = 2 independent 16-row tiles --------
// r2-r4 counters: resident blocks/CU ~ grid/940 regardless of VGPR/LDS caps ->
// per-CU workgroup-slot limited, not resource-limited. Pack 2 tiles (8 waves)
// per workgroup: per-wave code IDENTICAL to the proven 52us structure (1x
// per-thread chains — r3's 2x-chain mistake avoided); waves/workgroup doubles.
__global__ __launch_bounds__(512) void k_lstmfc(
    const _Float16* __restrict__ gout, const float* __restrict__ zeta,
    const uint32_t* __restrict__ wbuf,
    const float* __restrict__ fc_w, const float* __restrict__ fc_b,
    float* __restrict__ out) {
  const int m0 = blockIdx.x * 32;
  const int tid = threadIdx.x;
  const int wave = tid >> 6;        // 0..7
  const int grp = wave >> 2;        // tile 0/1
  const int gw = wave & 3;          // gate-col group within tile
  const int lane = tid & 63;
  const int col = lane & 15;
  const int quad = lane >> 4;
  const int tw = gw * 64 + lane;    // wbuf index (256-thread packing)

  // coalesced prologue: 92 dword loads, zero VALU (weights shared across tiles)
  float bias1[4], bias2[4], wx[4];
  H8U Bx[4], Bh1[4][2], Bh2[4][2];
#pragma unroll
  for (int g = 0; g < 4; ++g) {
    bias1[g] = __uint_as_float(wbuf[(0 + g) * 256 + tw]);
    bias2[g] = __uint_as_float(wbuf[(4 + g) * 256 + tw]);
    wx[g]    = __uint_as_float(wbuf[(8 + g) * 256 + tw]);
#pragma unroll
    for (int d = 0; d < 4; ++d) Bx[g].u[d] = wbuf[(12 + g * 4 + d) * 256 + tw];
#pragma unroll
    for (int c2 = 0; c2 < 2; ++c2)
#pragma unroll
      for (int d = 0; d < 4; ++d) {
        Bh1[g][c2].u[d] = wbuf[(28 + (g * 2 + c2) * 4 + d) * 256 + tw];
        Bh2[g][c2].u[d] = wbuf[(60 + (g * 2 + c2) * 4 + d) * 256 + tw];
      }
  }
  // loop-invariant MFMA C-operand bias vectors
  f32x4 bv1[4];
#pragma unroll
  for (int g = 0; g < 4; ++g) {
    f32x4 v = {bias1[g], bias1[g], bias1[g], bias1[g]};
    bv1[g] = v;
  }

  // per-tile LDS: h-exchange double-buffers aliased with FC buffer
  __shared__ union {
    struct {
      __align__(16) _Float16 hb1[2][16 * 72];
      __align__(16) _Float16 hb2[2][16 * 72];
    } h;                       // 9216 B
    float fcb[16][132];        // 8448 B
  } su[2];
  __shared__ float zbuf[TT][32];

  // zeta staging; per-ROW batch index (block 312 straddles the b boundary)
  if (tid < TT * 32) {
    int t = tid >> 5, ss = tid & 31;
    int m = m0 + ss;
    int bs = (m >= NN) ? 1 : 0;
    int ns = m - bs * NN;
    zbuf[t][ss] = zeta[((size_t)bs * TT + t) * NN + ns];
  }

  // gout row index IS the global m row (m = b*NN + n)
  const _Float16* gbase =
      gout + (size_t)(m0 + grp * 16 + col) * (TT * HG) + quad * 8;
  half8 A0 = *(const half8*)(gbase);

  // cell state carried pre-scaled by 2*L2E (see tanh2g)
  float c1[4] = {0.f, 0.f, 0.f, 0.f}, c2v[4] = {0.f, 0.f, 0.f, 0.f};
  float h1f[4], h2f[4];

  barrier_lds();   // zbuf visible; A0/weight prefetches stay in flight

#pragma unroll
  for (int t = 0; t < TT; ++t) {
    const int p = t & 1;
    if (t > 0) {
#pragma unroll
      for (int r = 0; r < 4; ++r) {
        int a = (quad * 4 + r) * 72 + 16 * gw + col;
        su[grp].h.hb1[p][a] = (_Float16)h1f[r];
        su[grp].h.hb2[p][a] = (_Float16)h2f[r];
      }
    }
    f32x4 a1[4], a2[4];
    const f32x4 z4 = *(const f32x4*)(&zbuf[t][grp * 16 + quad * 4]);
#pragma unroll
    for (int g = 0; g < 4; ++g) {
      a1[g] = __builtin_amdgcn_mfma_f32_16x16x32_f16(A0, Bx[g].v, bv1[g], 0, 0, 0);
#pragma unroll
      for (int r = 0; r < 4; ++r)
        a2[g][r] = fmaf(wx[g], z4[r], bias2[g]);
    }
    if (t < TT - 1) A0 = *(const half8*)(gbase + (t + 1) * HG);
    if (t > 0) {
      barrier_lds();
      const half8 A11 = *(const half8*)(&su[grp].h.hb1[p][col * 72 + quad * 8]);
      const half8 A21 = *(const half8*)(&su[grp].h.hb1[p][col * 72 + 32 + quad * 8]);
      const half8 A12 = *(const half8*)(&su[grp].h.hb2[p][col * 72 + quad * 8]);
      const half8 A22 = *(const half8*)(&su[grp].h.hb2[p][col * 72 + 32 + quad * 8]);
#pragma unroll
      for (int g = 0; g < 4; ++g) {
        a1[g] = __builtin_amdgcn_mfma_f32_16x16x32_f16(A11, Bh1[g][0].v, a1[g], 0, 0, 0);
        a1[g] = __builtin_amdgcn_mfma_f32_16x16x32_f16(A21, Bh1[g][1].v, a1[g], 0, 0, 0);
        a2[g] = __builtin_amdgcn_mfma_f32_16x16x32_f16(A12, Bh2[g][0].v, a2[g], 0, 0, 0);
        a2[g] = __builtin_amdgcn_mfma_f32_16x16x32_f16(A22, Bh2[g][1].v, a2[g], 0, 0, 0);
      }
    }
#pragma unroll
    for (int r = 0; r < 4; ++r) {
      float i1 = sigm2(a1[0][r]), f1 = sigm2(a1[1][r]);
      float g1 = tanh2g(a1[2][r]), o1 = sigm2(a1[3][r]);
      c1[r] = fmaf(f1, c1[r], i1 * g1);
      h1f[r] = o1 * tanh2(c1[r]);
      float i2 = sigm2(a2[0][r]), f2 = sigm2(a2[1][r]);
      float g2 = tanh2g(a2[2][r]), o2 = sigm2(a2[3][r]);
      c2v[r] = fmaf(f2, c2v[r], i2 * g2);
      h2f[r] = o2 * tanh2(c2v[r]);
    }
  }
  // alias hazard: all waves must finish their last hb reads before fcb writes
  barrier_lds();
#pragma unroll
  for (int r = 0; r < 4; ++r) {
    su[grp].fcb[quad * 4 + r][16 * gw + col] = h1f[r];
    su[grp].fcb[quad * 4 + r][64 + 16 * gw + col] = h2f[r];
  }
  barrier_lds();
  if (tid < 128) {
    int pp = tid >> 5, ss = tid & 31;
    int g2 = ss >> 4, sl = ss & 15;
    int m = m0 + ss;
    int bs = (m >= NN) ? 1 : 0;
    int ns = m - bs * NN;
    const f32x4* wr = (const f32x4*)(fc_w + pp * 128);
    const float* hv = su[g2].fcb[sl];
    float acc = fc_b[pp];
#pragma unroll
    for (int k = 0; k < 32; ++k) {
      f32x4 w4 = wr[k];
      acc += w4[0] * hv[4 * k] + w4[1] * hv[4 * k + 1] +
             w4[2] * hv[4 * k + 2] + w4[3] * hv[4 * k + 3];
    }
    out[((size_t)(bs * PP + pp)) * NN + ns] = acc;
  }
}

extern "C" void kernel_launch(void* const* d_in, const int* in_sizes, int n_in,
                              void* d_out, int out_size, void* d_ws, size_t ws_size,
                              hipStream_t stream) {
  (void)in_sizes; (void)n_in; (void)out_size; (void)ws_size;
  const float* era5  = (const float*)d_in[0];
  const float* zeta  = (const float*)d_in[1];
  const int*   eidx  = (const int*)d_in[2];
  const float* gcn_w = (const float*)d_in[3];
  const float* gcn_b = (const float*)d_in[4];
  const float* w_ih1 = (const float*)d_in[5];
  const float* w_hh1 = (const float*)d_in[6];
  const float* b_ih1 = (const float*)d_in[7];
  const float* b_hh1 = (const float*)d_in[8];
  const float* w_ih2 = (const float*)d_in[9];
  const float* w_hh2 = (const float*)d_in[10];
  const float* b_ih2 = (const float*)d_in[11];
  const float* b_hh2 = (const float*)d_in[12];
  const float* fc_w  = (const float*)d_in[13];
  const float* fc_b  = (const float*)d_in[14];
  float* out = (float*)d_out;

  char* ws = (char*)d_ws;
  int*      cnt  = (int*)(ws);                        // 40 KB
  int*      csr  = (int*)(ws + (64 << 10));           // 3.84 MB
  uint32_t* xt   = (uint32_t*)(ws + (4ull << 20));    // [S][N][64] fp16, 7.68 MB
  uint32_t* gout = (uint32_t*)(ws + (12ull << 20));   // [B*N][T][HG] fp16, 15.36 MB
  uint32_t* wbuf = (uint32_t*)(ws + (28ull << 20));   // 100*256*4 = 100 KB

  hipMemsetAsync(cnt, 0, NN * sizeof(int), stream);
  k_prepfill<<<FILL_BLKS + PREP_BLKS + 1, 256, 0, stream>>>(
      eidx, cnt, csr, era5, xt, gcn_w,
      w_ih1, w_hh1, b_ih1, b_hh1, w_ih2, w_hh2, b_ih2, b_hh2, wbuf);
  k_gather<<<SL * (NN / 4), 256, 0, stream>>>(xt, csr, cnt, gcn_b, wbuf,
                                              (_Float16*)gout);
  k_lstmfc<<<MM / 32, 512, 0, stream>>>((const _Float16*)gout, zeta, wbuf,
                                        fc_w, fc_b, out);
}